// Round 8
// baseline (60444.269 us; speedup 1.0000x reference)
//
#include <hip/hip_runtime.h>
#include <hip/hip_bf16.h>

// Problem: B=16,S=64 -> BS=1024 sequences, L=128 tokens, D=512, F=256 filters
// per conv width Kw in {3,4,5}, V=30000.
// out[bs, c*256 + f] = relu(max_t (conv_c(x)[t,f]) + b_c[f]), fp32.
//
// R5: slab + fragment-packed B -> 399 us (floors: TCP 164 / MFMA 199 / LDS 118
//     us) -> 2x over floor = unhidden L2 latency at 2 waves/SIMD.
// R6: 32x64 tiles + sched pin FAILED (500 us): halved intensity doubled the
//     TCP floor; sched_group_barrier didn't preserve the pipeline (VGPR=60).
// R7: 16 waves = 2m x 4n x 2-K-SPLIT, wave tile stays 64x64 (2x2 of
//     mfma_f32_32x32x16_bf16). 4 waves/SIMD for TLP; K-split doubles each
//     wave's inter-load time; 32x32 shape halves live frag regs so the
//     pipeline fits the 128-VGPR cap. B depth-2 prefetch, A JIT from padded
//     slab. Epilogue: K-split partners SUM via LDS before the row-max.
//     (R7 retry: renamed lane-half var that shadowed bias param b5.)

typedef __bf16 bf16x8 __attribute__((ext_vector_type(8)));
typedef float f32x4  __attribute__((ext_vector_type(4)));
typedef float f32x16 __attribute__((ext_vector_type(16)));

#define XROWS 132                     // 128 real + 4 zero pad (K=5 window)
#define XELEMS ((size_t)1024 * XROWS * 512)
#define SLAB_STRIDE 520               // 512 + 8 bf16 pad (bank spread)
#define SLAB_BYTES (XROWS * SLAB_STRIDE * 2)   // 137280 B
#define WQ_ELEMS 1572864              // 3072 chunks * 512 elem

__device__ __forceinline__ void async16(const void* g, void* l) {
    __builtin_amdgcn_global_load_lds(
        (const __attribute__((address_space(1))) void*)g,
        (__attribute__((address_space(3))) void*)l, 16, 0, 0);
}

// ---------------- pack_x: x[bs][t][d] = bf16(embed[text[bs,t], d]) ----------
__global__ void pack_x_kernel(const int* __restrict__ text,
                              const float* __restrict__ embed,
                              __bf16* __restrict__ x) {
    const int tid  = threadIdx.x;
    const int rr   = blockIdx.x * 4 + (tid >> 6);   // global row 0..135167
    const int lane = tid & 63;
    const int bs   = rr / XROWS;
    const int t    = rr - bs * XROWS;
    __bf16* dst = x + (size_t)rr * 512 + lane * 8;
    bf16x8 o = {};
    if (t < 128) {
        const int token = text[bs * 128 + t];
        const float* src = embed + (size_t)token * 512 + lane * 8;
        const float4 v0 = *(const float4*)(src);
        const float4 v1 = *(const float4*)(src + 4);
        o[0] = (__bf16)v0.x; o[1] = (__bf16)v0.y;
        o[2] = (__bf16)v0.z; o[3] = (__bf16)v0.w;
        o[4] = (__bf16)v1.x; o[5] = (__bf16)v1.y;
        o[6] = (__bf16)v1.z; o[7] = (__bf16)v1.w;
    }
    *(bf16x8*)dst = o;
}

// -------- pack_w: 32x32x16 B-fragment-ordered chunks ------------------------
// Chunk g = (c, gk, n32), 1024 B = 64 lanes x 16 B; gk = 16-k group, n32 =
// 32-filter group. Element (lane, j):
//   f = n32*32 + (lane&31), k = gk*16 + (lane>>5)*8 + j, tap = k>>9, d = k&511
//   src = w_c[f][d][tap]   (w layout [F][D][Kw]).
// Chunk bases: c0 = 0 (768), c1 = 768 (1024), c2 = 1792 (1280); total 3072.
__global__ void pack_w_kernel(const float* __restrict__ w3,
                              const float* __restrict__ w4,
                              const float* __restrict__ w5,
                              __bf16* __restrict__ wq) {
    const int t    = blockIdx.x * 256 + threadIdx.x;  // 0..196607
    const int g    = t >> 6;                          // chunk 0..3071
    const int lane = t & 63;
    int rel, Kw; const float* w;
    if (g < 768)       { rel = g;        Kw = 3; w = w3; }
    else if (g < 1792) { rel = g - 768;  Kw = 4; w = w4; }
    else               { rel = g - 1792; Kw = 5; w = w5; }
    const int gk  = rel >> 3;
    const int n32 = rel & 7;
    const int f   = n32 * 32 + (lane & 31);
    const int k0  = gk * 16 + (lane >> 5) * 8;        // never straddles a tap
    const int tap = k0 >> 9;
    const int d0  = k0 & 511;
    const float* src = w + ((size_t)f * 512 + d0) * Kw + tap;
    bf16x8 o;
#pragma unroll
    for (int j = 0; j < 8; ++j) o[j] = (__bf16)src[j * Kw];
    *(bf16x8*)(wq + (size_t)t * 8) = o;
}

// ---------------- slab-resident conv GEMM + max + bias + relu ---------------
// Grid 3072 = (bs, conv), XCD decode. 1024 thr = 16 waves: wm(2) x wn(4) x
// ks(2 K-split). Wave tile 64x64 = 2x2 of 32x32x16 bf16; wave handles kq
// (32-k units) with kq&1 == ks. A: persistent LDS slab (132x520), JIT reads.
// B: fragment-packed global chunks, depth-2 register prefetch. No barriers
// in the K-loop. Epilogue: ks-partners sum acc via LDS, then max/bias/relu.
__global__ __launch_bounds__(1024) void conv_gemm_kernel(
        const __bf16* __restrict__ x,
        const __bf16* __restrict__ wq,
        const float* __restrict__ b3,
        const float* __restrict__ b4,
        const float* __restrict__ b5,
        float* __restrict__ out) {
    extern __shared__ __bf16 slab[];   // XROWS x SLAB_STRIDE bf16

    const int tid  = threadIdx.x;
    const int wave = tid >> 6;
    const int lane = tid & 63;

    const int lin = blockIdx.x;
    const int xcd = lin & 7;
    const int idx = lin >> 3;             // 0..383
    const int bsh = idx / 3;
    const int c   = idx - bsh * 3;        // conv 0..2 (Kw = 3+c)
    const int bs  = bsh * 8 + xcd;        // 0..1023
    const int KW  = 3 + c;
    const int nkq = KW << 4;              // 48 / 64 / 80
    const int cbase = (c == 0) ? 0 : (c == 1) ? 393216 : 917504;  // elems

    const __bf16* xb = x + (size_t)bs * (XROWS * 512);

    // ---- stage slab once ----
    for (int r = wave; r < XROWS; r += 16)
        async16(xb + r * 512 + lane * 8, &slab[r * SLAB_STRIDE]);
    __syncthreads();

    // ---- wave decode ----
    const int wm = wave & 1;              // m64 group
    const int wn = (wave >> 1) & 3;       // n64 group
    const int ks = wave >> 3;             // K-split parity
    const int l31 = lane & 31, lh = lane >> 5;   // lane-in-32, lane half

    // A frag (32x32x16): row = wm*64 + mt*32 + l31 + tap, k = h*16 + lh*8 + j
    const __bf16* apb = slab + (wm * 64 + l31) * SLAB_STRIDE + lh * 8;
    // B frag: chunk (gk, n32) at elems cbase + (gk*8 + n32)*512; wave uses
    // n32 = wn*2 + {0,1}; loadB(kq): gk = 2kq, 2kq+1.
    const __bf16* bp = wq + cbase + (size_t)(wn * 2) * 512 + lane * 8;

    f32x16 acc[2][2] = {};
    bf16x8 B2[2][4];

    auto loadB = [&](bf16x8* d, int kq) {
        const __bf16* p = bp + (size_t)kq * 8192;
        d[0] = *(const bf16x8*)(p);          // gk0, n32a
        d[1] = *(const bf16x8*)(p + 512);    // gk0, n32b
        d[2] = *(const bf16x8*)(p + 4096);   // gk1, n32a
        d[3] = *(const bf16x8*)(p + 4608);   // gk1, n32b
    };

    loadB(B2[0], ks);
    loadB(B2[1], ks + 2);

    const int ni = nkq >> 1;              // 24 / 32 / 40 per-wave iters
#pragma unroll 4
    for (int i = 0; i < ni; ++i) {
        const int kq  = 2 * i + ks;       // this wave's K chunk (32 k)
        const int tap = kq >> 4;
        const int hh  = (kq & 15) << 1;   // first 16-k unit within tap
        const __bf16* a0 = apb + tap * SLAB_STRIDE + hh * 16;
        const int cur = i & 1;
        bf16x8 al = *(const bf16x8*)(a0);
        bf16x8 ah = *(const bf16x8*)(a0 + 32 * SLAB_STRIDE);
        acc[0][0] = __builtin_amdgcn_mfma_f32_32x32x16_bf16(al, B2[cur][0], acc[0][0], 0, 0, 0);
        acc[0][1] = __builtin_amdgcn_mfma_f32_32x32x16_bf16(al, B2[cur][1], acc[0][1], 0, 0, 0);
        acc[1][0] = __builtin_amdgcn_mfma_f32_32x32x16_bf16(ah, B2[cur][0], acc[1][0], 0, 0, 0);
        acc[1][1] = __builtin_amdgcn_mfma_f32_32x32x16_bf16(ah, B2[cur][1], acc[1][1], 0, 0, 0);
        al = *(const bf16x8*)(a0 + 16);
        ah = *(const bf16x8*)(a0 + 16 + 32 * SLAB_STRIDE);
        acc[0][0] = __builtin_amdgcn_mfma_f32_32x32x16_bf16(al, B2[cur][2], acc[0][0], 0, 0, 0);
        acc[0][1] = __builtin_amdgcn_mfma_f32_32x32x16_bf16(al, B2[cur][3], acc[0][1], 0, 0, 0);
        acc[1][0] = __builtin_amdgcn_mfma_f32_32x32x16_bf16(ah, B2[cur][2], acc[1][0], 0, 0, 0);
        acc[1][1] = __builtin_amdgcn_mfma_f32_32x32x16_bf16(ah, B2[cur][3], acc[1][1], 0, 0, 0);
        int kn = kq + 4;                  // prefetch depth 2 (wave-local)
        kn = (kn < nkq) ? kn : (nkq - 1); // uniform clamp; dummy never used
        loadB(B2[cur], kn);
    }

    // ---- epilogue ----
    __syncthreads();                      // slab A-data dead from here
    float* sf = (float*)slab;             // 34320 f32 available
    const int pid = wave & 7;             // (wm,wn) id shared by ks partners

    if (ks == 1) {                        // partner writes its partial sums
#pragma unroll
        for (int mt = 0; mt < 2; ++mt)
#pragma unroll
            for (int nt = 0; nt < 2; ++nt) {
                float* tb = sf + pid * 4096 + (mt * 2 + nt) * 1024 + lane * 16;
#pragma unroll
                for (int r = 0; r < 16; ++r) tb[r] = acc[mt][nt][r];
            }
    }
    __syncthreads();
    if (ks == 0) {                        // sum partials, THEN max over t
        const float* pf = sf + pid * 4096 + lane * 16;
#pragma unroll
        for (int mt = 0; mt < 2; ++mt)
#pragma unroll
            for (int nt = 0; nt < 2; ++nt) {
                const float* tb = pf + (mt * 2 + nt) * 1024;
#pragma unroll
                for (int r = 0; r < 16; ++r) acc[mt][nt][r] += tb[r];
            }
        // C layout 32x32: col = lane&31, row = (r&3) + 8*(r>>2) + 4*(lane>>5)
        const int Tv = 126 - c;           // valid t count
        float* red2 = sf + 32768;         // [2][256] wm-partials
#pragma unroll
        for (int nt = 0; nt < 2; ++nt) {
            float mx = -3.0e38f;
#pragma unroll
            for (int mt = 0; mt < 2; ++mt) {
                const int rbase = wm * 64 + mt * 32 + 4 * lh;
#pragma unroll
                for (int r = 0; r < 16; ++r) {
                    const int row = rbase + (r & 3) + 8 * (r >> 2);
                    const float v = acc[mt][nt][r];
                    if (row < Tv) mx = fmaxf(mx, v);
                }
            }
            mx = fmaxf(mx, __shfl_xor(mx, 32, 64));
            if (lh == 0)
                red2[wm * 256 + wn * 64 + nt * 32 + l31] = mx;
        }
    }
    __syncthreads();
    if (tid < 256) {
        const float* bias = (c == 0) ? b3 : (c == 1) ? b4 : b5;
        const float* red2 = sf + 32768;
        float v = fmaxf(red2[tid], red2[256 + tid]) + bias[tid];
        out[(size_t)bs * 768 + c * 256 + tid] = fmaxf(v, 0.f);
    }
}

extern "C" void kernel_launch(void* const* d_in, const int* in_sizes, int n_in,
                              void* d_out, int out_size, void* d_ws, size_t ws_size,
                              hipStream_t stream) {
    const int*   text  = (const int*)d_in[0];
    const float* embed = (const float*)d_in[1];
    const float* w3    = (const float*)d_in[2];
    const float* b3    = (const float*)d_in[3];
    const float* w4    = (const float*)d_in[4];
    const float* b4    = (const float*)d_in[5];
    const float* w5    = (const float*)d_in[6];
    const float* b5    = (const float*)d_in[7];
    float* out = (float*)d_out;

    __bf16* x  = (__bf16*)d_ws;                 // 1024*132*512 bf16 = 138.4 MB
    __bf16* wq = x + XELEMS;                    // 1572864 bf16 = 3.1 MB

    (void)hipFuncSetAttribute((const void*)conv_gemm_kernel,
                              hipFuncAttributeMaxDynamicSharedMemorySize,
                              SLAB_BYTES);

    pack_x_kernel<<<1024 * XROWS / 4, 256, 0, stream>>>(text, embed, x);
    pack_w_kernel<<<768, 256, 0, stream>>>(w3, w4, w5, wq);
    conv_gemm_kernel<<<3072, 1024, SLAB_BYTES, stream>>>(x, wq, b3, b4, b5, out);
}